// Round 9
// baseline (442.315 us; speedup 1.0000x reference)
//
#include <hip/hip_runtime.h>
#include <hip/hip_fp16.h>

#define N_NODES 100000
#define N_EDGES 1600000
#define D 128

#define NBIN 196            // coarse bins: dst>>9, 512 nodes each
#define NCHUNK 391          // edge chunks of 4096
#define CHUNK_E 4096
#define SCAN_TOT (NBIN * NCHUNK)   // 76636

typedef __attribute__((ext_vector_type(8))) _Float16 f16x8;
typedef __attribute__((ext_vector_type(4))) float f32x4;

__device__ __forceinline__ float h2f(ushort u) {
    __half_raw r; r.x = u;
    return __half2float(__half(r));
}
__device__ __forceinline__ ushort f2h(float f) {
    __half_raw r = __half_raw(__float2half(f));
    return r.x;
}

// ---------------- P1: coarse partition (LDS histograms, no global atomics) ---------

__global__ __launch_bounds__(256) void p1_hist(const int* __restrict__ dst,
                                               int* __restrict__ blockhist) {
    __shared__ int h[NBIN];
    int tid = threadIdx.x;
    for (int b = tid; b < NBIN; b += 256) h[b] = 0;
    __syncthreads();
    int base = blockIdx.x * CHUNK_E;
#pragma unroll
    for (int j = 0; j < 16; ++j) {
        int i = base + j * 256 + tid;
        if (i < N_EDGES) atomicAdd(&h[dst[i] >> 9], 1);
    }
    __syncthreads();
    for (int b = tid; b < NBIN; b += 256)
        blockhist[b * NCHUNK + blockIdx.x] = h[b];
}

__global__ __launch_bounds__(1024) void p1_scan(int* __restrict__ bh,
                                                int* __restrict__ row_ptr) {
    __shared__ int s[1024];
    int tid = threadIdx.x;
    const int CH = (SCAN_TOT + 1023) / 1024;   // 75
    int b0 = tid * CH;
    int sum = 0;
    for (int i = 0; i < CH; ++i) {
        int idx = b0 + i;
        if (idx < SCAN_TOT) sum += bh[idx];
    }
    s[tid] = sum;
    __syncthreads();
    for (int off = 1; off < 1024; off <<= 1) {
        int v = (tid >= off) ? s[tid - off] : 0;
        __syncthreads();
        s[tid] += v;
        __syncthreads();
    }
    int run = s[tid] - sum;                    // exclusive base of this thread's range
    for (int i = 0; i < CH; ++i) {
        int idx = b0 + i;
        if (idx < SCAN_TOT) {
            int v = bh[idx];
            bh[idx] = run;                     // in-place exclusive scan
            run += v;
        }
    }
    if (tid == 0) row_ptr[N_NODES] = N_EDGES;
}

// record: {src | dstLocal<<17, w1h | w2h<<16}
__global__ __launch_bounds__(256) void p1_scatter(const int* __restrict__ src,
                                                  const int* __restrict__ dst,
                                                  const float* __restrict__ w1,
                                                  const float* __restrict__ w2,
                                                  const int* __restrict__ bh,
                                                  uint2* __restrict__ part) {
    __shared__ int cur[NBIN];
    int tid = threadIdx.x;
    for (int b = tid; b < NBIN; b += 256) cur[b] = bh[b * NCHUNK + blockIdx.x];
    __syncthreads();
    int base = blockIdx.x * CHUNK_E;
#pragma unroll
    for (int j = 0; j < 16; ++j) {
        int i = base + j * 256 + tid;
        if (i < N_EDGES) {
            int d = dst[i];
            int pos = atomicAdd(&cur[d >> 9], 1);
            uint2 e;
            e.x = (unsigned)src[i] | ((unsigned)(d & 511) << 17);
            e.y = (unsigned)f2h(w1[i]) | ((unsigned)f2h(w2[i]) << 16);
            part[pos] = e;
        }
    }
}

// ---------------- P2: per-bin fine grouping -> exact CSR, deg_inv folded ----------

__global__ __launch_bounds__(256) void p2_kernel(const int* __restrict__ bh,
                                                 const uint2* __restrict__ part,
                                                 int* __restrict__ row_ptr,
                                                 uint2* __restrict__ packed) {
    __shared__ int deg2[512];
    __shared__ int cur[512];
    __shared__ int sb[256];
    int tid = threadIdx.x;
    int bin = blockIdx.x;
    int base = bh[bin * NCHUNK];
    int endv = (bin == NBIN - 1) ? N_EDGES : bh[(bin + 1) * NCHUNK];
    int cnt = endv - base;
    deg2[tid] = 0; deg2[tid + 256] = 0;
    __syncthreads();
    for (int k = tid; k < cnt; k += 256)
        atomicAdd(&deg2[part[base + k].x >> 17], 1);
    __syncthreads();
    int s0 = deg2[2 * tid], s1 = deg2[2 * tid + 1];
    int ts = s0 + s1;
    sb[tid] = ts;
    __syncthreads();
    for (int off = 1; off < 256; off <<= 1) {
        int v = (tid >= off) ? sb[tid - off] : 0;
        __syncthreads();
        sb[tid] += v;
        __syncthreads();
    }
    int ex = sb[tid] - ts;                     // exclusive within bin
    cur[2 * tid] = ex;
    cur[2 * tid + 1] = ex + s0;
    int node0 = bin * 512 + 2 * tid;
    if (node0 < N_NODES)     row_ptr[node0]     = base + ex;
    if (node0 + 1 < N_NODES) row_ptr[node0 + 1] = base + ex + s0;
    __syncthreads();
    for (int k = tid; k < cnt; k += 256) {
        uint2 r = part[base + k];
        int local = r.x >> 17;
        float di = 1.0f / (float)deg2[local];
        int pos = base + atomicAdd(&cur[local], 1);
        uint2 e;
        e.x = r.x & 0x1FFFFu;
        e.y = (unsigned)f2h(h2f((ushort)(r.y & 0xFFFFu)) * di)
            | ((unsigned)f2h(h2f((ushort)(r.y >> 16)) * di) << 16);
        packed[pos] = e;
    }
}

// ---------------- fp32 -> fp16 convert (8 elems/thread) ----------------

__global__ __launch_bounds__(256) void cvt_f16_kernel(const float* __restrict__ in,
                                                      ushort* __restrict__ out) {
    long i = ((long)blockIdx.x * 256 + threadIdx.x) * 8;
    const float4 a = *reinterpret_cast<const float4*>(&in[i]);
    const float4 b = *reinterpret_cast<const float4*>(&in[i + 4]);
    ushort4 u0, u1;
    u0.x = f2h(a.x); u0.y = f2h(a.y); u0.z = f2h(a.z); u0.w = f2h(a.w);
    u1.x = f2h(b.x); u1.y = f2h(b.y); u1.z = f2h(b.z); u1.w = f2h(b.w);
    *reinterpret_cast<ushort4*>(&out[i]) = u0;
    *reinterpret_cast<ushort4*>(&out[i + 4]) = u1;
}

// ---------------- W tiling: fragment-ordered fp16 ----------------
// addr(k,n) = ((k>>3)*128 + n)*8 + (k&7)  -> b-frag for (kgroup, n) is 16B contiguous

__global__ __launch_bounds__(256) void wtile_kernel(const float* __restrict__ W,
                                                    ushort* __restrict__ th,
                                                    int total) {
    int i = blockIdx.x * 256 + threadIdx.x;
    if (i < total) {
        int k = i >> 7, n = i & 127;
        int addr = (((k >> 3) << 7) + n) * 8 + (k & 7);
        th[addr] = f2h(W[i]);
    }
}

// ---------------- SpMM: CSR gather of fp16 rows + leaky-relu ----------------
// wave-per-node; 32 lanes cover a row (ushort4/lane); lane-half = edge parity.

__global__ __launch_bounds__(256) void spmm_kernel(const ushort* __restrict__ xin,
                                                   const uint2* __restrict__ edges,
                                                   const int* __restrict__ row_ptr,
                                                   ushort* __restrict__ out,
                                                   int widx) {
    int wid = threadIdx.x >> 6;
    int half = (threadIdx.x >> 5) & 1;     // edge parity handled by this lane-half
    int l = threadIdx.x & 31;              // dim group: dims 4l..4l+3
    int n = blockIdx.x * 4 + wid;
    int beg = row_ptr[n], end = row_ptr[n + 1];
    float a0 = 0.f, a1 = 0.f, a2 = 0.f, a3 = 0.f;

    int i = beg;
    for (; i + 7 < end; i += 8) {
        const uint2 e0 = edges[i + half];
        const uint2 e1 = edges[i + 2 + half];
        const uint2 e2 = edges[i + 4 + half];
        const uint2 e3 = edges[i + 6 + half];
        float w0 = h2f((ushort)(widx ? (e0.y >> 16) : (e0.y & 0xFFFFu)));
        float w1 = h2f((ushort)(widx ? (e1.y >> 16) : (e1.y & 0xFFFFu)));
        float w2 = h2f((ushort)(widx ? (e2.y >> 16) : (e2.y & 0xFFFFu)));
        float w3 = h2f((ushort)(widx ? (e3.y >> 16) : (e3.y & 0xFFFFu)));
        const ushort4 u0 = *reinterpret_cast<const ushort4*>(&xin[(long)e0.x * D + l * 4]);
        const ushort4 u1 = *reinterpret_cast<const ushort4*>(&xin[(long)e1.x * D + l * 4]);
        const ushort4 u2 = *reinterpret_cast<const ushort4*>(&xin[(long)e2.x * D + l * 4]);
        const ushort4 u3 = *reinterpret_cast<const ushort4*>(&xin[(long)e3.x * D + l * 4]);
        a0 += w0 * h2f(u0.x) + w1 * h2f(u1.x) + w2 * h2f(u2.x) + w3 * h2f(u3.x);
        a1 += w0 * h2f(u0.y) + w1 * h2f(u1.y) + w2 * h2f(u2.y) + w3 * h2f(u3.y);
        a2 += w0 * h2f(u0.z) + w1 * h2f(u1.z) + w2 * h2f(u2.z) + w3 * h2f(u3.z);
        a3 += w0 * h2f(u0.w) + w1 * h2f(u1.w) + w2 * h2f(u2.w) + w3 * h2f(u3.w);
    }
    for (; i + 1 < end; i += 2) {
        const uint2 e0 = edges[i + half];
        float w0 = h2f((ushort)(widx ? (e0.y >> 16) : (e0.y & 0xFFFFu)));
        const ushort4 u0 = *reinterpret_cast<const ushort4*>(&xin[(long)e0.x * D + l * 4]);
        a0 += w0 * h2f(u0.x);
        a1 += w0 * h2f(u0.y);
        a2 += w0 * h2f(u0.z);
        a3 += w0 * h2f(u0.w);
    }
    if (i < end) {
        const uint2 e0 = edges[i];
        float w0 = half ? 0.f : h2f((ushort)(widx ? (e0.y >> 16) : (e0.y & 0xFFFFu)));
        const ushort4 u0 = *reinterpret_cast<const ushort4*>(&xin[(long)e0.x * D + l * 4]);
        a0 += w0 * h2f(u0.x);
        a1 += w0 * h2f(u0.y);
        a2 += w0 * h2f(u0.z);
        a3 += w0 * h2f(u0.w);
    }

    a0 += __shfl_xor(a0, 32, 64);
    a1 += __shfl_xor(a1, 32, 64);
    a2 += __shfl_xor(a2, 32, 64);
    a3 += __shfl_xor(a3, 32, 64);

    if (half == 0) {
        a0 = a0 > 0.f ? a0 : 0.01f * a0;
        a1 = a1 > 0.f ? a1 : 0.01f * a1;
        a2 = a2 > 0.f ? a2 : 0.01f * a2;
        a3 = a3 > 0.f ? a3 : 0.01f * a3;
        ushort4 r;
        r.x = f2h(a0); r.y = f2h(a1); r.z = f2h(a2); r.w = f2h(a3);
        *reinterpret_cast<ushort4*>(&out[(long)n * D + l * 4]) = r;
    }
}

// ---------------- MFMA fp16 GEMM: out = relu([in1|in2] @ W + b) as fp16 ----------

__global__ __launch_bounds__(256) void gemm_mfma_kernel(
        const ushort* __restrict__ in1,
        const ushort* __restrict__ in2,
        const ushort* __restrict__ Wt,
        const float* __restrict__ bias,
        ushort* __restrict__ outp) {
    int tid = threadIdx.x;
    int w = tid >> 6, l = tid & 63;
    int c = l & 15, kg = l >> 4;
    int base_m = blockIdx.x * 128 + w * 32;
    int r0 = base_m + c;       if (r0 >= N_NODES) r0 = N_NODES - 1;
    int r1 = base_m + 16 + c;  if (r1 >= N_NODES) r1 = N_NODES - 1;

    f32x4 acc0[8], acc1[8];
#pragma unroll
    for (int ni = 0; ni < 8; ++ni) { acc0[ni] = (f32x4)0.f; acc1[ni] = (f32x4)0.f; }

    for (int ks = 0; ks < 8; ++ks) {
        int kb = (ks & 3) * 32 + kg * 8;
        const ushort* src = (ks < 4) ? in1 : in2;
        f16x8 a0 = *reinterpret_cast<const f16x8*>(&src[(long)r0 * D + kb]);
        f16x8 a1 = *reinterpret_cast<const f16x8*>(&src[(long)r1 * D + kb]);
        const ushort* wb = &Wt[(size_t)((ks * 4 + kg) * 128) * 8];
#pragma unroll
        for (int ni = 0; ni < 8; ++ni) {
            const f16x8 b = *reinterpret_cast<const f16x8*>(&wb[(ni * 16 + c) * 8]);
            acc0[ni] = __builtin_amdgcn_mfma_f32_16x16x32_f16(a0, b, acc0[ni], 0, 0, 0);
            acc1[ni] = __builtin_amdgcn_mfma_f32_16x16x32_f16(a1, b, acc1[ni], 0, 0, 0);
        }
    }

    float bv[8];
#pragma unroll
    for (int ni = 0; ni < 8; ++ni) bv[ni] = bias[ni * 16 + c];
#pragma unroll
    for (int mi = 0; mi < 2; ++mi) {
        int rowb = base_m + mi * 16 + kg * 4;
#pragma unroll
        for (int r = 0; r < 4; ++r) {
            int row = rowb + r;
            if (row < N_NODES) {
#pragma unroll
                for (int ni = 0; ni < 8; ++ni) {
                    float v = (mi ? acc1[ni][r] : acc0[ni][r]) + bv[ni];
                    v = v > 0.f ? v : 0.f;
                    outp[(long)row * D + ni * 16 + c] = f2h(v);
                }
            }
        }
    }
}

// ---------------- Classifier: out = relu(H @ Wl1 + bl1) @ Wl2 + bl2 ----------------

__global__ __launch_bounds__(256) void cls_mfma_kernel(
        const ushort* __restrict__ H,
        const ushort* __restrict__ Wt,
        const float* __restrict__ bl1, const float* __restrict__ Wl2,
        const float* __restrict__ bl2, float* __restrict__ out) {
    int tid = threadIdx.x;
    int w = tid >> 6, l = tid & 63;
    int c = l & 15, kg = l >> 4;
    int base_m = blockIdx.x * 128 + w * 32;
    int r0 = base_m + c;       if (r0 >= N_NODES) r0 = N_NODES - 1;
    int r1 = base_m + 16 + c;  if (r1 >= N_NODES) r1 = N_NODES - 1;

    f32x4 acc0[8], acc1[8];
#pragma unroll
    for (int ni = 0; ni < 8; ++ni) { acc0[ni] = (f32x4)0.f; acc1[ni] = (f32x4)0.f; }

    for (int ks = 0; ks < 4; ++ks) {
        int kb = ks * 32 + kg * 8;
        f16x8 a0 = *reinterpret_cast<const f16x8*>(&H[(long)r0 * D + kb]);
        f16x8 a1 = *reinterpret_cast<const f16x8*>(&H[(long)r1 * D + kb]);
        const ushort* wb = &Wt[(size_t)((ks * 4 + kg) * 128) * 8];
#pragma unroll
        for (int ni = 0; ni < 8; ++ni) {
            const f16x8 b = *reinterpret_cast<const f16x8*>(&wb[(ni * 16 + c) * 8]);
            acc0[ni] = __builtin_amdgcn_mfma_f32_16x16x32_f16(a0, b, acc0[ni], 0, 0, 0);
            acc1[ni] = __builtin_amdgcn_mfma_f32_16x16x32_f16(a1, b, acc1[ni], 0, 0, 0);
        }
    }

    float b1v[8]; float2 w2v[8];
#pragma unroll
    for (int ni = 0; ni < 8; ++ni) {
        b1v[ni] = bl1[ni * 16 + c];
        w2v[ni] = *reinterpret_cast<const float2*>(&Wl2[(ni * 16 + c) * 2]);
    }
#pragma unroll
    for (int mi = 0; mi < 2; ++mi) {
        float p0[4] = {0.f, 0.f, 0.f, 0.f};
        float p1[4] = {0.f, 0.f, 0.f, 0.f};
#pragma unroll
        for (int ni = 0; ni < 8; ++ni) {
#pragma unroll
            for (int r = 0; r < 4; ++r) {
                float t = (mi ? acc1[ni][r] : acc0[ni][r]) + b1v[ni];
                t = t > 0.f ? t : 0.f;
                p0[r] += t * w2v[ni].x;
                p1[r] += t * w2v[ni].y;
            }
        }
#pragma unroll
        for (int r = 0; r < 4; ++r) {
#pragma unroll
            for (int m = 1; m < 16; m <<= 1) {
                p0[r] += __shfl_xor(p0[r], m, 64);
                p1[r] += __shfl_xor(p1[r], m, 64);
            }
        }
        if (c < 2) {
            int rowb = base_m + mi * 16 + kg * 4;
#pragma unroll
            for (int r = 0; r < 4; ++r) {
                int row = rowb + r;
                if (row < N_NODES)
                    out[(long)row * 2 + c] = (c == 0 ? p0[r] : p1[r]) + bl2[c];
            }
        }
    }
}

// ---------------- launch ----------------

extern "C" void kernel_launch(void* const* d_in, const int* in_sizes, int n_in,
                              void* d_out, int out_size, void* d_ws, size_t ws_size,
                              hipStream_t stream) {
    const float* x   = (const float*)d_in[0];
    const int* esrc  = (const int*)d_in[1];
    const int* edst  = (const int*)d_in[2];
    const float* ew1 = (const float*)d_in[3];
    const float* ew2 = (const float*)d_in[4];
    const float* W1  = (const float*)d_in[5];
    const float* b1  = (const float*)d_in[6];
    const float* W2  = (const float*)d_in[7];
    const float* b2  = (const float*)d_in[8];
    const float* Wl1 = (const float*)d_in[9];
    const float* bl1 = (const float*)d_in[10];
    const float* Wl2 = (const float*)d_in[11];
    const float* bl2 = (const float*)d_in[12];
    float* out = (float*)d_out;

    char* p = (char*)d_ws;
    ushort* Af      = (ushort*)p;          p += (size_t)N_NODES * D * 2;   // agg (fp16)
    ushort* h1f     = (ushort*)p;          p += (size_t)N_NODES * D * 2;   // h1/h2 (fp16, aliased)
    ushort* xf      = (ushort*)p;          p += (size_t)N_NODES * D * 2;   // x (fp16)
    int* row_ptr    = (int*)p;             p += (size_t)(N_NODES + 16) * 4;
    int* blockhist  = (int*)p;             p += (size_t)SCAN_TOT * 4;      // 307 KB
    uint2* part     = (uint2*)p;           p += (size_t)N_EDGES * 8;       // 12.8 MB
    uint2* packed   = (uint2*)p;           p += (size_t)N_EDGES * 8;       // 12.8 MB
    ushort* W1t     = (ushort*)p;          p += 2 * D * D * 2;
    ushort* W2t     = (ushort*)p;          p += 2 * D * D * 2;
    ushort* Wl1t    = (ushort*)p;          p += D * D * 2;

    // CSR build: two-level partition, LDS atomics only
    p1_hist<<<NCHUNK, 256, 0, stream>>>(edst, blockhist);
    p1_scan<<<1, 1024, 0, stream>>>(blockhist, row_ptr);
    p1_scatter<<<NCHUNK, 256, 0, stream>>>(esrc, edst, ew1, ew2, blockhist, part);
    p2_kernel<<<NBIN, 256, 0, stream>>>(blockhist, part, row_ptr, packed);

    cvt_f16_kernel<<<(N_NODES * D) / (256 * 8), 256, 0, stream>>>(x, xf);
    wtile_kernel<<<(2 * D * D + 255) / 256, 256, 0, stream>>>(W1, W1t, 2 * D * D);
    wtile_kernel<<<(2 * D * D + 255) / 256, 256, 0, stream>>>(W2, W2t, 2 * D * D);
    wtile_kernel<<<(D * D + 255) / 256, 256, 0, stream>>>(Wl1, Wl1t, D * D);

    int ggrid = (N_NODES + 127) / 128;   // 782

    // layer 1
    spmm_kernel<<<N_NODES / 4, 256, 0, stream>>>(xf, packed, row_ptr, Af, 0);
    gemm_mfma_kernel<<<ggrid, 256, 0, stream>>>(xf, Af, W1t, b1, h1f);
    // layer 2 (h2 overwrites h1 in place: each wave reads only its own 32 rows first)
    spmm_kernel<<<N_NODES / 4, 256, 0, stream>>>(h1f, packed, row_ptr, Af, 1);
    gemm_mfma_kernel<<<ggrid, 256, 0, stream>>>(h1f, Af, W2t, b2, h1f);
    // classifier
    cls_mfma_kernel<<<ggrid, 256, 0, stream>>>(h1f, Wl1t, bl1, Wl2, bl2, out);
}

// Round 10
// 300.736 us; speedup vs baseline: 1.4708x; 1.4708x over previous
//
#include <hip/hip_runtime.h>
#include <hip/hip_fp16.h>

#define N_NODES 100000
#define N_EDGES 1600000
#define D 128

#define NBIN 196            // coarse bins: dst>>9, 512 nodes each
#define NCHUNK 391          // edge chunks of 4096
#define CHUNK_E 4096
#define SCAN_TOT (NBIN * NCHUNK)   // 76636
#define SC_NB ((SCAN_TOT + 1023) / 1024)   // 75

typedef __attribute__((ext_vector_type(8))) _Float16 f16x8;
typedef __attribute__((ext_vector_type(4))) float f32x4;

__device__ __forceinline__ float h2f(ushort u) {
    __half_raw r; r.x = u;
    return __half2float(__half(r));
}
__device__ __forceinline__ ushort f2h(float f) {
    __half_raw r = __half_raw(__float2half(f));
    return r.x;
}

// ---------------- P1: coarse partition (LDS histograms, no global atomics) ---------

__global__ __launch_bounds__(256) void p1_hist(const int* __restrict__ dst,
                                               int* __restrict__ blockhist) {
    __shared__ int h[NBIN];
    int tid = threadIdx.x;
    for (int b = tid; b < NBIN; b += 256) h[b] = 0;
    __syncthreads();
    int base = blockIdx.x * CHUNK_E;
#pragma unroll
    for (int j = 0; j < 16; ++j) {
        int i = base + j * 256 + tid;
        if (i < N_EDGES) atomicAdd(&h[dst[i] >> 9], 1);
    }
    __syncthreads();
    for (int b = tid; b < NBIN; b += 256)
        blockhist[b * NCHUNK + blockIdx.x] = h[b];
}

// ---- hierarchical exclusive scan of blockhist[SCAN_TOT] (in place) ----

__global__ __launch_bounds__(256) void scan_a(const int* __restrict__ bh,
                                              int* __restrict__ partials) {
    __shared__ int sums[256];
    int tid = threadIdx.x;
    int base = blockIdx.x * 1024 + tid * 4;
    int s = 0;
#pragma unroll
    for (int i = 0; i < 4; ++i) {
        int idx = base + i;
        if (idx < SCAN_TOT) s += bh[idx];
    }
    sums[tid] = s;
    __syncthreads();
#pragma unroll
    for (int off = 128; off > 0; off >>= 1) {
        if (tid < off) sums[tid] += sums[tid + off];
        __syncthreads();
    }
    if (tid == 0) partials[blockIdx.x] = sums[0];
}

__global__ __launch_bounds__(128) void scan_b(int* __restrict__ partials,
                                              int* __restrict__ row_ptr) {
    __shared__ int s[128];
    int tid = threadIdx.x;
    int v = (tid < SC_NB) ? partials[tid] : 0;
    s[tid] = v;
    __syncthreads();
    for (int off = 1; off < 128; off <<= 1) {
        int t = (tid >= off) ? s[tid - off] : 0;
        __syncthreads();
        s[tid] += t;
        __syncthreads();
    }
    if (tid < SC_NB) partials[tid] = s[tid] - v;   // exclusive block offsets
    if (tid == 0) row_ptr[N_NODES] = N_EDGES;
}

__global__ __launch_bounds__(256) void scan_c(int* __restrict__ bh,
                                              const int* __restrict__ partials) {
    __shared__ int tsum[256];
    int tid = threadIdx.x;
    int base = blockIdx.x * 1024 + tid * 4;
    int d[4];
#pragma unroll
    for (int i = 0; i < 4; ++i)
        d[i] = (base + i < SCAN_TOT) ? bh[base + i] : 0;
    int s = d[0] + d[1] + d[2] + d[3];
    tsum[tid] = s;
    __syncthreads();
    for (int off = 1; off < 256; off <<= 1) {
        int t = (tid >= off) ? tsum[tid - off] : 0;
        __syncthreads();
        tsum[tid] += t;
        __syncthreads();
    }
    int run = partials[blockIdx.x] + tsum[tid] - s;   // exclusive start
#pragma unroll
    for (int i = 0; i < 4; ++i) {
        int idx = base + i;
        if (idx < SCAN_TOT) {
            bh[idx] = run;
            run += d[i];
        }
    }
}

// record: {src | dstLocal<<17, w1h | w2h<<16}
__global__ __launch_bounds__(256) void p1_scatter(const int* __restrict__ src,
                                                  const int* __restrict__ dst,
                                                  const float* __restrict__ w1,
                                                  const float* __restrict__ w2,
                                                  const int* __restrict__ bh,
                                                  uint2* __restrict__ part) {
    __shared__ int cur[NBIN];
    int tid = threadIdx.x;
    for (int b = tid; b < NBIN; b += 256) cur[b] = bh[b * NCHUNK + blockIdx.x];
    __syncthreads();
    int base = blockIdx.x * CHUNK_E;
#pragma unroll
    for (int j = 0; j < 16; ++j) {
        int i = base + j * 256 + tid;
        if (i < N_EDGES) {
            int d = dst[i];
            int pos = atomicAdd(&cur[d >> 9], 1);
            uint2 e;
            e.x = (unsigned)src[i] | ((unsigned)(d & 511) << 17);
            e.y = (unsigned)f2h(w1[i]) | ((unsigned)f2h(w2[i]) << 16);
            part[pos] = e;
        }
    }
}

// ---------------- P2: per-bin fine grouping -> exact CSR, deg_inv folded ----------

__global__ __launch_bounds__(256) void p2_kernel(const int* __restrict__ bh,
                                                 const uint2* __restrict__ part,
                                                 int* __restrict__ row_ptr,
                                                 uint2* __restrict__ packed) {
    __shared__ int deg2[512];
    __shared__ int cur[512];
    __shared__ int sb[256];
    int tid = threadIdx.x;
    int bin = blockIdx.x;
    int base = bh[bin * NCHUNK];
    int endv = (bin == NBIN - 1) ? N_EDGES : bh[(bin + 1) * NCHUNK];
    int cnt = endv - base;
    deg2[tid] = 0; deg2[tid + 256] = 0;
    __syncthreads();
    for (int k = tid; k < cnt; k += 256)
        atomicAdd(&deg2[part[base + k].x >> 17], 1);
    __syncthreads();
    int s0 = deg2[2 * tid], s1 = deg2[2 * tid + 1];
    int ts = s0 + s1;
    sb[tid] = ts;
    __syncthreads();
    for (int off = 1; off < 256; off <<= 1) {
        int v = (tid >= off) ? sb[tid - off] : 0;
        __syncthreads();
        sb[tid] += v;
        __syncthreads();
    }
    int ex = sb[tid] - ts;                     // exclusive within bin
    cur[2 * tid] = ex;
    cur[2 * tid + 1] = ex + s0;
    int node0 = bin * 512 + 2 * tid;
    if (node0 < N_NODES)     row_ptr[node0]     = base + ex;
    if (node0 + 1 < N_NODES) row_ptr[node0 + 1] = base + ex + s0;
    __syncthreads();
    for (int k = tid; k < cnt; k += 256) {
        uint2 r = part[base + k];
        int local = r.x >> 17;
        float di = 1.0f / (float)deg2[local];
        int pos = base + atomicAdd(&cur[local], 1);
        uint2 e;
        e.x = r.x & 0x1FFFFu;
        e.y = (unsigned)f2h(h2f((ushort)(r.y & 0xFFFFu)) * di)
            | ((unsigned)f2h(h2f((ushort)(r.y >> 16)) * di) << 16);
        packed[pos] = e;
    }
}

// ---------------- fp32 -> fp16 convert (8 elems/thread) ----------------

__global__ __launch_bounds__(256) void cvt_f16_kernel(const float* __restrict__ in,
                                                      ushort* __restrict__ out) {
    long i = ((long)blockIdx.x * 256 + threadIdx.x) * 8;
    const float4 a = *reinterpret_cast<const float4*>(&in[i]);
    const float4 b = *reinterpret_cast<const float4*>(&in[i + 4]);
    ushort4 u0, u1;
    u0.x = f2h(a.x); u0.y = f2h(a.y); u0.z = f2h(a.z); u0.w = f2h(a.w);
    u1.x = f2h(b.x); u1.y = f2h(b.y); u1.z = f2h(b.z); u1.w = f2h(b.w);
    *reinterpret_cast<ushort4*>(&out[i]) = u0;
    *reinterpret_cast<ushort4*>(&out[i + 4]) = u1;
}

// ---------------- W tiling: fragment-ordered fp16 ----------------
// addr(k,n) = ((k>>3)*128 + n)*8 + (k&7)  -> b-frag for (kgroup, n) is 16B contiguous

__global__ __launch_bounds__(256) void wtile_kernel(const float* __restrict__ W,
                                                    ushort* __restrict__ th,
                                                    int total) {
    int i = blockIdx.x * 256 + threadIdx.x;
    if (i < total) {
        int k = i >> 7, n = i & 127;
        int addr = (((k >> 3) << 7) + n) * 8 + (k & 7);
        th[addr] = f2h(W[i]);
    }
}

// ---------------- SpMM: CSR gather of fp16 rows + leaky-relu ----------------
// wave-per-node; 32 lanes cover a row (ushort4/lane); lane-half = edge parity.

__global__ __launch_bounds__(256) void spmm_kernel(const ushort* __restrict__ xin,
                                                   const uint2* __restrict__ edges,
                                                   const int* __restrict__ row_ptr,
                                                   ushort* __restrict__ out,
                                                   int widx) {
    int wid = threadIdx.x >> 6;
    int half = (threadIdx.x >> 5) & 1;     // edge parity handled by this lane-half
    int l = threadIdx.x & 31;              // dim group: dims 4l..4l+3
    int n = blockIdx.x * 4 + wid;
    int beg = row_ptr[n], end = row_ptr[n + 1];
    float a0 = 0.f, a1 = 0.f, a2 = 0.f, a3 = 0.f;

    int i = beg;
    for (; i + 7 < end; i += 8) {
        const uint2 e0 = edges[i + half];
        const uint2 e1 = edges[i + 2 + half];
        const uint2 e2 = edges[i + 4 + half];
        const uint2 e3 = edges[i + 6 + half];
        float w0 = h2f((ushort)(widx ? (e0.y >> 16) : (e0.y & 0xFFFFu)));
        float w1 = h2f((ushort)(widx ? (e1.y >> 16) : (e1.y & 0xFFFFu)));
        float w2 = h2f((ushort)(widx ? (e2.y >> 16) : (e2.y & 0xFFFFu)));
        float w3 = h2f((ushort)(widx ? (e3.y >> 16) : (e3.y & 0xFFFFu)));
        const ushort4 u0 = *reinterpret_cast<const ushort4*>(&xin[(long)e0.x * D + l * 4]);
        const ushort4 u1 = *reinterpret_cast<const ushort4*>(&xin[(long)e1.x * D + l * 4]);
        const ushort4 u2 = *reinterpret_cast<const ushort4*>(&xin[(long)e2.x * D + l * 4]);
        const ushort4 u3 = *reinterpret_cast<const ushort4*>(&xin[(long)e3.x * D + l * 4]);
        a0 += w0 * h2f(u0.x) + w1 * h2f(u1.x) + w2 * h2f(u2.x) + w3 * h2f(u3.x);
        a1 += w0 * h2f(u0.y) + w1 * h2f(u1.y) + w2 * h2f(u2.y) + w3 * h2f(u3.y);
        a2 += w0 * h2f(u0.z) + w1 * h2f(u1.z) + w2 * h2f(u2.z) + w3 * h2f(u3.z);
        a3 += w0 * h2f(u0.w) + w1 * h2f(u1.w) + w2 * h2f(u2.w) + w3 * h2f(u3.w);
    }
    for (; i + 1 < end; i += 2) {
        const uint2 e0 = edges[i + half];
        float w0 = h2f((ushort)(widx ? (e0.y >> 16) : (e0.y & 0xFFFFu)));
        const ushort4 u0 = *reinterpret_cast<const ushort4*>(&xin[(long)e0.x * D + l * 4]);
        a0 += w0 * h2f(u0.x);
        a1 += w0 * h2f(u0.y);
        a2 += w0 * h2f(u0.z);
        a3 += w0 * h2f(u0.w);
    }
    if (i < end) {
        const uint2 e0 = edges[i];
        float w0 = half ? 0.f : h2f((ushort)(widx ? (e0.y >> 16) : (e0.y & 0xFFFFu)));
        const ushort4 u0 = *reinterpret_cast<const ushort4*>(&xin[(long)e0.x * D + l * 4]);
        a0 += w0 * h2f(u0.x);
        a1 += w0 * h2f(u0.y);
        a2 += w0 * h2f(u0.z);
        a3 += w0 * h2f(u0.w);
    }

    a0 += __shfl_xor(a0, 32, 64);
    a1 += __shfl_xor(a1, 32, 64);
    a2 += __shfl_xor(a2, 32, 64);
    a3 += __shfl_xor(a3, 32, 64);

    if (half == 0) {
        a0 = a0 > 0.f ? a0 : 0.01f * a0;
        a1 = a1 > 0.f ? a1 : 0.01f * a1;
        a2 = a2 > 0.f ? a2 : 0.01f * a2;
        a3 = a3 > 0.f ? a3 : 0.01f * a3;
        ushort4 r;
        r.x = f2h(a0); r.y = f2h(a1); r.z = f2h(a2); r.w = f2h(a3);
        *reinterpret_cast<ushort4*>(&out[(long)n * D + l * 4]) = r;
    }
}

// ---------------- MFMA fp16 GEMM: out = relu([in1|in2] @ W + b) as fp16 ----------

__global__ __launch_bounds__(256) void gemm_mfma_kernel(
        const ushort* __restrict__ in1,
        const ushort* __restrict__ in2,
        const ushort* __restrict__ Wt,
        const float* __restrict__ bias,
        ushort* __restrict__ outp) {
    int tid = threadIdx.x;
    int w = tid >> 6, l = tid & 63;
    int c = l & 15, kg = l >> 4;
    int base_m = blockIdx.x * 128 + w * 32;
    int r0 = base_m + c;       if (r0 >= N_NODES) r0 = N_NODES - 1;
    int r1 = base_m + 16 + c;  if (r1 >= N_NODES) r1 = N_NODES - 1;

    f32x4 acc0[8], acc1[8];
#pragma unroll
    for (int ni = 0; ni < 8; ++ni) { acc0[ni] = (f32x4)0.f; acc1[ni] = (f32x4)0.f; }

    for (int ks = 0; ks < 8; ++ks) {
        int kb = (ks & 3) * 32 + kg * 8;
        const ushort* src = (ks < 4) ? in1 : in2;
        f16x8 a0 = *reinterpret_cast<const f16x8*>(&src[(long)r0 * D + kb]);
        f16x8 a1 = *reinterpret_cast<const f16x8*>(&src[(long)r1 * D + kb]);
        const ushort* wb = &Wt[(size_t)((ks * 4 + kg) * 128) * 8];
#pragma unroll
        for (int ni = 0; ni < 8; ++ni) {
            const f16x8 b = *reinterpret_cast<const f16x8*>(&wb[(ni * 16 + c) * 8]);
            acc0[ni] = __builtin_amdgcn_mfma_f32_16x16x32_f16(a0, b, acc0[ni], 0, 0, 0);
            acc1[ni] = __builtin_amdgcn_mfma_f32_16x16x32_f16(a1, b, acc1[ni], 0, 0, 0);
        }
    }

    float bv[8];
#pragma unroll
    for (int ni = 0; ni < 8; ++ni) bv[ni] = bias[ni * 16 + c];
#pragma unroll
    for (int mi = 0; mi < 2; ++mi) {
        int rowb = base_m + mi * 16 + kg * 4;
#pragma unroll
        for (int r = 0; r < 4; ++r) {
            int row = rowb + r;
            if (row < N_NODES) {
#pragma unroll
                for (int ni = 0; ni < 8; ++ni) {
                    float v = (mi ? acc1[ni][r] : acc0[ni][r]) + bv[ni];
                    v = v > 0.f ? v : 0.f;
                    outp[(long)row * D + ni * 16 + c] = f2h(v);
                }
            }
        }
    }
}

// ---------------- Classifier: out = relu(H @ Wl1 + bl1) @ Wl2 + bl2 ----------------

__global__ __launch_bounds__(256) void cls_mfma_kernel(
        const ushort* __restrict__ H,
        const ushort* __restrict__ Wt,
        const float* __restrict__ bl1, const float* __restrict__ Wl2,
        const float* __restrict__ bl2, float* __restrict__ out) {
    int tid = threadIdx.x;
    int w = tid >> 6, l = tid & 63;
    int c = l & 15, kg = l >> 4;
    int base_m = blockIdx.x * 128 + w * 32;
    int r0 = base_m + c;       if (r0 >= N_NODES) r0 = N_NODES - 1;
    int r1 = base_m + 16 + c;  if (r1 >= N_NODES) r1 = N_NODES - 1;

    f32x4 acc0[8], acc1[8];
#pragma unroll
    for (int ni = 0; ni < 8; ++ni) { acc0[ni] = (f32x4)0.f; acc1[ni] = (f32x4)0.f; }

    for (int ks = 0; ks < 4; ++ks) {
        int kb = ks * 32 + kg * 8;
        f16x8 a0 = *reinterpret_cast<const f16x8*>(&H[(long)r0 * D + kb]);
        f16x8 a1 = *reinterpret_cast<const f16x8*>(&H[(long)r1 * D + kb]);
        const ushort* wb = &Wt[(size_t)((ks * 4 + kg) * 128) * 8];
#pragma unroll
        for (int ni = 0; ni < 8; ++ni) {
            const f16x8 b = *reinterpret_cast<const f16x8*>(&wb[(ni * 16 + c) * 8]);
            acc0[ni] = __builtin_amdgcn_mfma_f32_16x16x32_f16(a0, b, acc0[ni], 0, 0, 0);
            acc1[ni] = __builtin_amdgcn_mfma_f32_16x16x32_f16(a1, b, acc1[ni], 0, 0, 0);
        }
    }

    float b1v[8]; float2 w2v[8];
#pragma unroll
    for (int ni = 0; ni < 8; ++ni) {
        b1v[ni] = bl1[ni * 16 + c];
        w2v[ni] = *reinterpret_cast<const float2*>(&Wl2[(ni * 16 + c) * 2]);
    }
#pragma unroll
    for (int mi = 0; mi < 2; ++mi) {
        float p0[4] = {0.f, 0.f, 0.f, 0.f};
        float p1[4] = {0.f, 0.f, 0.f, 0.f};
#pragma unroll
        for (int ni = 0; ni < 8; ++ni) {
#pragma unroll
            for (int r = 0; r < 4; ++r) {
                float t = (mi ? acc1[ni][r] : acc0[ni][r]) + b1v[ni];
                t = t > 0.f ? t : 0.f;
                p0[r] += t * w2v[ni].x;
                p1[r] += t * w2v[ni].y;
            }
        }
#pragma unroll
        for (int r = 0; r < 4; ++r) {
#pragma unroll
            for (int m = 1; m < 16; m <<= 1) {
                p0[r] += __shfl_xor(p0[r], m, 64);
                p1[r] += __shfl_xor(p1[r], m, 64);
            }
        }
        if (c < 2) {
            int rowb = base_m + mi * 16 + kg * 4;
#pragma unroll
            for (int r = 0; r < 4; ++r) {
                int row = rowb + r;
                if (row < N_NODES)
                    out[(long)row * 2 + c] = (c == 0 ? p0[r] : p1[r]) + bl2[c];
            }
        }
    }
}

// ---------------- launch ----------------

extern "C" void kernel_launch(void* const* d_in, const int* in_sizes, int n_in,
                              void* d_out, int out_size, void* d_ws, size_t ws_size,
                              hipStream_t stream) {
    const float* x   = (const float*)d_in[0];
    const int* esrc  = (const int*)d_in[1];
    const int* edst  = (const int*)d_in[2];
    const float* ew1 = (const float*)d_in[3];
    const float* ew2 = (const float*)d_in[4];
    const float* W1  = (const float*)d_in[5];
    const float* b1  = (const float*)d_in[6];
    const float* W2  = (const float*)d_in[7];
    const float* b2  = (const float*)d_in[8];
    const float* Wl1 = (const float*)d_in[9];
    const float* bl1 = (const float*)d_in[10];
    const float* Wl2 = (const float*)d_in[11];
    const float* bl2 = (const float*)d_in[12];
    float* out = (float*)d_out;

    char* p = (char*)d_ws;
    ushort* Af      = (ushort*)p;          p += (size_t)N_NODES * D * 2;   // agg (fp16)
    ushort* h1f     = (ushort*)p;          p += (size_t)N_NODES * D * 2;   // h1/h2 (fp16, aliased)
    ushort* xf      = (ushort*)p;          p += (size_t)N_NODES * D * 2;   // x (fp16)
    int* row_ptr    = (int*)p;             p += (size_t)(N_NODES + 16) * 4;
    int* blockhist  = (int*)p;             p += (size_t)SCAN_TOT * 4;      // 307 KB
    int* partials   = (int*)p;             p += 128 * 4;
    uint2* part     = (uint2*)p;           p += (size_t)N_EDGES * 8;       // 12.8 MB
    uint2* packed   = (uint2*)p;           p += (size_t)N_EDGES * 8;       // 12.8 MB
    ushort* W1t     = (ushort*)p;          p += 2 * D * D * 2;
    ushort* W2t     = (ushort*)p;          p += 2 * D * D * 2;
    ushort* Wl1t    = (ushort*)p;          p += D * D * 2;

    // CSR build: two-level partition, LDS atomics only, hierarchical scan
    p1_hist<<<NCHUNK, 256, 0, stream>>>(edst, blockhist);
    scan_a<<<SC_NB, 256, 0, stream>>>(blockhist, partials);
    scan_b<<<1, 128, 0, stream>>>(partials, row_ptr);
    scan_c<<<SC_NB, 256, 0, stream>>>(blockhist, partials);
    p1_scatter<<<NCHUNK, 256, 0, stream>>>(esrc, edst, ew1, ew2, blockhist, part);
    p2_kernel<<<NBIN, 256, 0, stream>>>(blockhist, part, row_ptr, packed);

    cvt_f16_kernel<<<(N_NODES * D) / (256 * 8), 256, 0, stream>>>(x, xf);
    wtile_kernel<<<(2 * D * D + 255) / 256, 256, 0, stream>>>(W1, W1t, 2 * D * D);
    wtile_kernel<<<(2 * D * D + 255) / 256, 256, 0, stream>>>(W2, W2t, 2 * D * D);
    wtile_kernel<<<(D * D + 255) / 256, 256, 0, stream>>>(Wl1, Wl1t, D * D);

    int ggrid = (N_NODES + 127) / 128;   // 782

    // layer 1
    spmm_kernel<<<N_NODES / 4, 256, 0, stream>>>(xf, packed, row_ptr, Af, 0);
    gemm_mfma_kernel<<<ggrid, 256, 0, stream>>>(xf, Af, W1t, b1, h1f);
    // layer 2 (h2 overwrites h1 in place: each wave reads only its own 32 rows first)
    spmm_kernel<<<N_NODES / 4, 256, 0, stream>>>(h1f, packed, row_ptr, Af, 1);
    gemm_mfma_kernel<<<ggrid, 256, 0, stream>>>(h1f, Af, W2t, b2, h1f);
    // classifier
    cls_mfma_kernel<<<ggrid, 256, 0, stream>>>(h1f, Wl1t, bl1, Wl2, bl2, out);
}

// Round 11
// 294.248 us; speedup vs baseline: 1.5032x; 1.0220x over previous
//
#include <hip/hip_runtime.h>
#include <hip/hip_fp16.h>

#define N_NODES 100000
#define N_EDGES 1600000
#define D 128

#define NBIN 196            // coarse bins: dst>>9, 512 nodes each
#define NCHUNK 391          // edge chunks of 4096
#define CHUNK_E 4096
#define SCAN_TOT (NBIN * NCHUNK)   // 76636
#define SC_NB ((SCAN_TOT + 1023) / 1024)   // 75

typedef __attribute__((ext_vector_type(8))) _Float16 f16x8;
typedef __attribute__((ext_vector_type(4))) float f32x4;
typedef __attribute__((ext_vector_type(8))) unsigned short u16x8;

__device__ __forceinline__ float h2f(ushort u) {
    __half_raw r; r.x = u;
    return __half2float(__half(r));
}
__device__ __forceinline__ ushort f2h(float f) {
    __half_raw r = __half_raw(__float2half(f));
    return r.x;
}

// ---------------- P1: coarse partition (LDS histograms, no global atomics) ---------

__global__ __launch_bounds__(256) void p1_hist(const int* __restrict__ dst,
                                               int* __restrict__ blockhist) {
    __shared__ int h[NBIN];
    int tid = threadIdx.x;
    for (int b = tid; b < NBIN; b += 256) h[b] = 0;
    __syncthreads();
    int base = blockIdx.x * CHUNK_E;
#pragma unroll
    for (int j = 0; j < 16; ++j) {
        int i = base + j * 256 + tid;
        if (i < N_EDGES) atomicAdd(&h[dst[i] >> 9], 1);
    }
    __syncthreads();
    for (int b = tid; b < NBIN; b += 256)
        blockhist[b * NCHUNK + blockIdx.x] = h[b];
}

// ---- hierarchical exclusive scan of blockhist[SCAN_TOT] (in place) ----

__global__ __launch_bounds__(256) void scan_a(const int* __restrict__ bh,
                                              int* __restrict__ partials) {
    __shared__ int sums[256];
    int tid = threadIdx.x;
    int base = blockIdx.x * 1024 + tid * 4;
    int s = 0;
#pragma unroll
    for (int i = 0; i < 4; ++i) {
        int idx = base + i;
        if (idx < SCAN_TOT) s += bh[idx];
    }
    sums[tid] = s;
    __syncthreads();
#pragma unroll
    for (int off = 128; off > 0; off >>= 1) {
        if (tid < off) sums[tid] += sums[tid + off];
        __syncthreads();
    }
    if (tid == 0) partials[blockIdx.x] = sums[0];
}

__global__ __launch_bounds__(128) void scan_b(int* __restrict__ partials,
                                              int* __restrict__ row_ptr) {
    __shared__ int s[128];
    int tid = threadIdx.x;
    int v = (tid < SC_NB) ? partials[tid] : 0;
    s[tid] = v;
    __syncthreads();
    for (int off = 1; off < 128; off <<= 1) {
        int t = (tid >= off) ? s[tid - off] : 0;
        __syncthreads();
        s[tid] += t;
        __syncthreads();
    }
    if (tid < SC_NB) partials[tid] = s[tid] - v;   // exclusive block offsets
    if (tid == 0) row_ptr[N_NODES] = N_EDGES;
}

__global__ __launch_bounds__(256) void scan_c(int* __restrict__ bh,
                                              const int* __restrict__ partials) {
    __shared__ int tsum[256];
    int tid = threadIdx.x;
    int base = blockIdx.x * 1024 + tid * 4;
    int d[4];
#pragma unroll
    for (int i = 0; i < 4; ++i)
        d[i] = (base + i < SCAN_TOT) ? bh[base + i] : 0;
    int s = d[0] + d[1] + d[2] + d[3];
    tsum[tid] = s;
    __syncthreads();
    for (int off = 1; off < 256; off <<= 1) {
        int t = (tid >= off) ? tsum[tid - off] : 0;
        __syncthreads();
        tsum[tid] += t;
        __syncthreads();
    }
    int run = partials[blockIdx.x] + tsum[tid] - s;   // exclusive start
#pragma unroll
    for (int i = 0; i < 4; ++i) {
        int idx = base + i;
        if (idx < SCAN_TOT) {
            bh[idx] = run;
            run += d[i];
        }
    }
}

// record: {src | dstLocal<<17, w1h | w2h<<16}
__global__ __launch_bounds__(256) void p1_scatter(const int* __restrict__ src,
                                                  const int* __restrict__ dst,
                                                  const float* __restrict__ w1,
                                                  const float* __restrict__ w2,
                                                  const int* __restrict__ bh,
                                                  uint2* __restrict__ part) {
    __shared__ int cur[NBIN];
    int tid = threadIdx.x;
    for (int b = tid; b < NBIN; b += 256) cur[b] = bh[b * NCHUNK + blockIdx.x];
    __syncthreads();
    int base = blockIdx.x * CHUNK_E;
#pragma unroll
    for (int j = 0; j < 16; ++j) {
        int i = base + j * 256 + tid;
        if (i < N_EDGES) {
            int d = dst[i];
            int pos = atomicAdd(&cur[d >> 9], 1);
            uint2 e;
            e.x = (unsigned)src[i] | ((unsigned)(d & 511) << 17);
            e.y = (unsigned)f2h(w1[i]) | ((unsigned)f2h(w2[i]) << 16);
            part[pos] = e;
        }
    }
}

// ---------------- P2: per-bin fine grouping -> exact CSR, deg_inv folded ----------

__global__ __launch_bounds__(256) void p2_kernel(const int* __restrict__ bh,
                                                 const uint2* __restrict__ part,
                                                 int* __restrict__ row_ptr,
                                                 uint2* __restrict__ packed) {
    __shared__ int deg2[512];
    __shared__ int cur[512];
    __shared__ int sb[256];
    int tid = threadIdx.x;
    int bin = blockIdx.x;
    int base = bh[bin * NCHUNK];
    int endv = (bin == NBIN - 1) ? N_EDGES : bh[(bin + 1) * NCHUNK];
    int cnt = endv - base;
    deg2[tid] = 0; deg2[tid + 256] = 0;
    __syncthreads();
    for (int k = tid; k < cnt; k += 256)
        atomicAdd(&deg2[part[base + k].x >> 17], 1);
    __syncthreads();
    int s0 = deg2[2 * tid], s1 = deg2[2 * tid + 1];
    int ts = s0 + s1;
    sb[tid] = ts;
    __syncthreads();
    for (int off = 1; off < 256; off <<= 1) {
        int v = (tid >= off) ? sb[tid - off] : 0;
        __syncthreads();
        sb[tid] += v;
        __syncthreads();
    }
    int ex = sb[tid] - ts;                     // exclusive within bin
    cur[2 * tid] = ex;
    cur[2 * tid + 1] = ex + s0;
    int node0 = bin * 512 + 2 * tid;
    if (node0 < N_NODES)     row_ptr[node0]     = base + ex;
    if (node0 + 1 < N_NODES) row_ptr[node0 + 1] = base + ex + s0;
    __syncthreads();
    for (int k = tid; k < cnt; k += 256) {
        uint2 r = part[base + k];
        int local = r.x >> 17;
        float di = 1.0f / (float)deg2[local];
        int pos = base + atomicAdd(&cur[local], 1);
        uint2 e;
        e.x = r.x & 0x1FFFFu;
        e.y = (unsigned)f2h(h2f((ushort)(r.y & 0xFFFFu)) * di)
            | ((unsigned)f2h(h2f((ushort)(r.y >> 16)) * di) << 16);
        packed[pos] = e;
    }
}

// ---------------- fp32 -> fp16 convert (8 elems/thread) ----------------

__global__ __launch_bounds__(256) void cvt_f16_kernel(const float* __restrict__ in,
                                                      ushort* __restrict__ out) {
    long i = ((long)blockIdx.x * 256 + threadIdx.x) * 8;
    const float4 a = *reinterpret_cast<const float4*>(&in[i]);
    const float4 b = *reinterpret_cast<const float4*>(&in[i + 4]);
    ushort4 u0, u1;
    u0.x = f2h(a.x); u0.y = f2h(a.y); u0.z = f2h(a.z); u0.w = f2h(a.w);
    u1.x = f2h(b.x); u1.y = f2h(b.y); u1.z = f2h(b.z); u1.w = f2h(b.w);
    *reinterpret_cast<ushort4*>(&out[i]) = u0;
    *reinterpret_cast<ushort4*>(&out[i + 4]) = u1;
}

// ---------------- W tiling: fragment-ordered fp16 ----------------
// addr(k,n) = ((k>>3)*128 + n)*8 + (k&7)  -> b-frag for (kgroup, n) is 16B contiguous

__global__ __launch_bounds__(256) void wtile_kernel(const float* __restrict__ W,
                                                    ushort* __restrict__ th,
                                                    int total) {
    int i = blockIdx.x * 256 + threadIdx.x;
    if (i < total) {
        int k = i >> 7, n = i & 127;
        int addr = (((k >> 3) << 7) + n) * 8 + (k & 7);
        th[addr] = f2h(W[i]);
    }
}

// ---------------- SpMM: CSR gather of fp16 rows + leaky-relu ----------------
// wave-per-node; 16 lanes cover a row (ushort8/lane); lane>>4 = edge parity (4-way).
// One gather instruction covers 4 edges; up to 4 gathers in flight.

__global__ __launch_bounds__(256) void spmm_kernel(const ushort* __restrict__ xin,
                                                   const uint2* __restrict__ edges,
                                                   const int* __restrict__ row_ptr,
                                                   ushort* __restrict__ out,
                                                   int widx) {
    int wid = threadIdx.x >> 6;
    int lane = threadIdx.x & 63;
    int par = lane >> 4;                   // edge parity 0..3
    int dl = lane & 15;                    // dim group: dims 8*dl..8*dl+7
    int n = blockIdx.x * 4 + wid;
    int beg = row_ptr[n], end = row_ptr[n + 1];
    float a[8] = {0.f, 0.f, 0.f, 0.f, 0.f, 0.f, 0.f, 0.f};

    int i = beg;
    for (; i + 15 < end; i += 16) {
        const uint2 e0 = edges[i + par];
        const uint2 e1 = edges[i + 4 + par];
        const uint2 e2 = edges[i + 8 + par];
        const uint2 e3 = edges[i + 12 + par];
        float w0 = h2f((ushort)(widx ? (e0.y >> 16) : (e0.y & 0xFFFFu)));
        float w1 = h2f((ushort)(widx ? (e1.y >> 16) : (e1.y & 0xFFFFu)));
        float w2 = h2f((ushort)(widx ? (e2.y >> 16) : (e2.y & 0xFFFFu)));
        float w3 = h2f((ushort)(widx ? (e3.y >> 16) : (e3.y & 0xFFFFu)));
        const u16x8 u0 = *reinterpret_cast<const u16x8*>(&xin[(long)e0.x * D + dl * 8]);
        const u16x8 u1 = *reinterpret_cast<const u16x8*>(&xin[(long)e1.x * D + dl * 8]);
        const u16x8 u2 = *reinterpret_cast<const u16x8*>(&xin[(long)e2.x * D + dl * 8]);
        const u16x8 u3 = *reinterpret_cast<const u16x8*>(&xin[(long)e3.x * D + dl * 8]);
#pragma unroll
        for (int j = 0; j < 8; ++j)
            a[j] += w0 * h2f(u0[j]) + w1 * h2f(u1[j]) + w2 * h2f(u2[j]) + w3 * h2f(u3[j]);
    }
    for (; i + 7 < end; i += 8) {
        const uint2 e0 = edges[i + par];
        const uint2 e1 = edges[i + 4 + par];
        float w0 = h2f((ushort)(widx ? (e0.y >> 16) : (e0.y & 0xFFFFu)));
        float w1 = h2f((ushort)(widx ? (e1.y >> 16) : (e1.y & 0xFFFFu)));
        const u16x8 u0 = *reinterpret_cast<const u16x8*>(&xin[(long)e0.x * D + dl * 8]);
        const u16x8 u1 = *reinterpret_cast<const u16x8*>(&xin[(long)e1.x * D + dl * 8]);
#pragma unroll
        for (int j = 0; j < 8; ++j)
            a[j] += w0 * h2f(u0[j]) + w1 * h2f(u1[j]);
    }
    for (; i < end; i += 4) {
        int idx = i + par;
        bool act = idx < end;
        const uint2 e0 = edges[act ? idx : end - 1];
        float w0 = act ? h2f((ushort)(widx ? (e0.y >> 16) : (e0.y & 0xFFFFu))) : 0.f;
        const u16x8 u0 = *reinterpret_cast<const u16x8*>(&xin[(long)e0.x * D + dl * 8]);
#pragma unroll
        for (int j = 0; j < 8; ++j)
            a[j] += w0 * h2f(u0[j]);
    }

    // combine the 4 edge-parity groups (lane ^ 16, lane ^ 32)
#pragma unroll
    for (int j = 0; j < 8; ++j) {
        a[j] += __shfl_xor(a[j], 16, 64);
        a[j] += __shfl_xor(a[j], 32, 64);
    }

    if (par == 0) {
        ushort4 r0, r1;
        float v;
        v = a[0]; v = v > 0.f ? v : 0.01f * v; r0.x = f2h(v);
        v = a[1]; v = v > 0.f ? v : 0.01f * v; r0.y = f2h(v);
        v = a[2]; v = v > 0.f ? v : 0.01f * v; r0.z = f2h(v);
        v = a[3]; v = v > 0.f ? v : 0.01f * v; r0.w = f2h(v);
        v = a[4]; v = v > 0.f ? v : 0.01f * v; r1.x = f2h(v);
        v = a[5]; v = v > 0.f ? v : 0.01f * v; r1.y = f2h(v);
        v = a[6]; v = v > 0.f ? v : 0.01f * v; r1.z = f2h(v);
        v = a[7]; v = v > 0.f ? v : 0.01f * v; r1.w = f2h(v);
        *reinterpret_cast<ushort4*>(&out[(long)n * D + dl * 8]) = r0;
        *reinterpret_cast<ushort4*>(&out[(long)n * D + dl * 8 + 4]) = r1;
    }
}

// ---------------- MFMA fp16 GEMM: out = relu([in1|in2] @ W + b) as fp16 ----------

__global__ __launch_bounds__(256) void gemm_mfma_kernel(
        const ushort* __restrict__ in1,
        const ushort* __restrict__ in2,
        const ushort* __restrict__ Wt,
        const float* __restrict__ bias,
        ushort* __restrict__ outp) {
    int tid = threadIdx.x;
    int w = tid >> 6, l = tid & 63;
    int c = l & 15, kg = l >> 4;
    int base_m = blockIdx.x * 128 + w * 32;
    int r0 = base_m + c;       if (r0 >= N_NODES) r0 = N_NODES - 1;
    int r1 = base_m + 16 + c;  if (r1 >= N_NODES) r1 = N_NODES - 1;

    f32x4 acc0[8], acc1[8];
#pragma unroll
    for (int ni = 0; ni < 8; ++ni) { acc0[ni] = (f32x4)0.f; acc1[ni] = (f32x4)0.f; }

    for (int ks = 0; ks < 8; ++ks) {
        int kb = (ks & 3) * 32 + kg * 8;
        const ushort* src = (ks < 4) ? in1 : in2;
        f16x8 a0 = *reinterpret_cast<const f16x8*>(&src[(long)r0 * D + kb]);
        f16x8 a1 = *reinterpret_cast<const f16x8*>(&src[(long)r1 * D + kb]);
        const ushort* wb = &Wt[(size_t)((ks * 4 + kg) * 128) * 8];
#pragma unroll
        for (int ni = 0; ni < 8; ++ni) {
            const f16x8 b = *reinterpret_cast<const f16x8*>(&wb[(ni * 16 + c) * 8]);
            acc0[ni] = __builtin_amdgcn_mfma_f32_16x16x32_f16(a0, b, acc0[ni], 0, 0, 0);
            acc1[ni] = __builtin_amdgcn_mfma_f32_16x16x32_f16(a1, b, acc1[ni], 0, 0, 0);
        }
    }

    float bv[8];
#pragma unroll
    for (int ni = 0; ni < 8; ++ni) bv[ni] = bias[ni * 16 + c];
#pragma unroll
    for (int mi = 0; mi < 2; ++mi) {
        int rowb = base_m + mi * 16 + kg * 4;
#pragma unroll
        for (int r = 0; r < 4; ++r) {
            int row = rowb + r;
            if (row < N_NODES) {
#pragma unroll
                for (int ni = 0; ni < 8; ++ni) {
                    float v = (mi ? acc1[ni][r] : acc0[ni][r]) + bv[ni];
                    v = v > 0.f ? v : 0.f;
                    outp[(long)row * D + ni * 16 + c] = f2h(v);
                }
            }
        }
    }
}

// ---------------- Fused layer-2 GEMM + classifier ----------------
// Phase A: h2 = relu([h1|A] @ W2 + b2) -> per-wave LDS tile (never to global)
// Phase B: out = relu(h2 @ Wl1 + bl1) @ Wl2 + bl2

#define LSTR 136   // LDS row stride in shorts

__global__ __launch_bounds__(256) void gemm2_cls_kernel(
        const ushort* __restrict__ in1,
        const ushort* __restrict__ in2,
        const ushort* __restrict__ W2t,
        const float* __restrict__ b2,
        const ushort* __restrict__ Wl1t,
        const float* __restrict__ bl1,
        const float* __restrict__ Wl2,
        const float* __restrict__ bl2,
        float* __restrict__ out) {
    __shared__ __align__(16) ushort lds_h2[4][32][LSTR];
    int tid = threadIdx.x;
    int w = tid >> 6, l = tid & 63;
    int c = l & 15, kg = l >> 4;
    int base_m = blockIdx.x * 128 + w * 32;
    int r0 = base_m + c;       if (r0 >= N_NODES) r0 = N_NODES - 1;
    int r1 = base_m + 16 + c;  if (r1 >= N_NODES) r1 = N_NODES - 1;

    // ---- phase A: h2 fragments ----
    f32x4 acc0[8], acc1[8];
#pragma unroll
    for (int ni = 0; ni < 8; ++ni) { acc0[ni] = (f32x4)0.f; acc1[ni] = (f32x4)0.f; }

    for (int ks = 0; ks < 8; ++ks) {
        int kb = (ks & 3) * 32 + kg * 8;
        const ushort* src = (ks < 4) ? in1 : in2;
        f16x8 a0 = *reinterpret_cast<const f16x8*>(&src[(long)r0 * D + kb]);
        f16x8 a1 = *reinterpret_cast<const f16x8*>(&src[(long)r1 * D + kb]);
        const ushort* wb = &W2t[(size_t)((ks * 4 + kg) * 128) * 8];
#pragma unroll
        for (int ni = 0; ni < 8; ++ni) {
            const f16x8 b = *reinterpret_cast<const f16x8*>(&wb[(ni * 16 + c) * 8]);
            acc0[ni] = __builtin_amdgcn_mfma_f32_16x16x32_f16(a0, b, acc0[ni], 0, 0, 0);
            acc1[ni] = __builtin_amdgcn_mfma_f32_16x16x32_f16(a1, b, acc1[ni], 0, 0, 0);
        }
    }

    float bv[8];
#pragma unroll
    for (int ni = 0; ni < 8; ++ni) bv[ni] = b2[ni * 16 + c];
#pragma unroll
    for (int mi = 0; mi < 2; ++mi) {
#pragma unroll
        for (int r = 0; r < 4; ++r) {
            int lrow = mi * 16 + kg * 4 + r;
#pragma unroll
            for (int ni = 0; ni < 8; ++ni) {
                float v = (mi ? acc1[ni][r] : acc0[ni][r]) + bv[ni];
                v = v > 0.f ? v : 0.f;
                lds_h2[w][lrow][ni * 16 + c] = f2h(v);
            }
        }
    }
    __syncthreads();   // wave-private tiles, but cheap insurance for LDS ordering

    // ---- phase B: classifier on the wave's 32 h2 rows ----
    f32x4 bcc0[8], bcc1[8];
#pragma unroll
    for (int ni = 0; ni < 8; ++ni) { bcc0[ni] = (f32x4)0.f; bcc1[ni] = (f32x4)0.f; }

    for (int ks = 0; ks < 4; ++ks) {
        int kb = ks * 32 + kg * 8;
        f16x8 a0 = *reinterpret_cast<const f16x8*>(&lds_h2[w][c][kb]);
        f16x8 a1 = *reinterpret_cast<const f16x8*>(&lds_h2[w][16 + c][kb]);
        const ushort* wb = &Wl1t[(size_t)((ks * 4 + kg) * 128) * 8];
#pragma unroll
        for (int ni = 0; ni < 8; ++ni) {
            const f16x8 b = *reinterpret_cast<const f16x8*>(&wb[(ni * 16 + c) * 8]);
            bcc0[ni] = __builtin_amdgcn_mfma_f32_16x16x32_f16(a0, b, bcc0[ni], 0, 0, 0);
            bcc1[ni] = __builtin_amdgcn_mfma_f32_16x16x32_f16(a1, b, bcc1[ni], 0, 0, 0);
        }
    }

    float b1v[8]; float2 w2v[8];
#pragma unroll
    for (int ni = 0; ni < 8; ++ni) {
        b1v[ni] = bl1[ni * 16 + c];
        w2v[ni] = *reinterpret_cast<const float2*>(&Wl2[(ni * 16 + c) * 2]);
    }
#pragma unroll
    for (int mi = 0; mi < 2; ++mi) {
        float p0[4] = {0.f, 0.f, 0.f, 0.f};
        float p1[4] = {0.f, 0.f, 0.f, 0.f};
#pragma unroll
        for (int ni = 0; ni < 8; ++ni) {
#pragma unroll
            for (int r = 0; r < 4; ++r) {
                float t = (mi ? bcc1[ni][r] : bcc0[ni][r]) + b1v[ni];
                t = t > 0.f ? t : 0.f;
                p0[r] += t * w2v[ni].x;
                p1[r] += t * w2v[ni].y;
            }
        }
#pragma unroll
        for (int r = 0; r < 4; ++r) {
#pragma unroll
            for (int m = 1; m < 16; m <<= 1) {
                p0[r] += __shfl_xor(p0[r], m, 64);
                p1[r] += __shfl_xor(p1[r], m, 64);
            }
        }
        if (c < 2) {
            int rowb = base_m + mi * 16 + kg * 4;
#pragma unroll
            for (int r = 0; r < 4; ++r) {
                int row = rowb + r;
                if (row < N_NODES)
                    out[(long)row * 2 + c] = (c == 0 ? p0[r] : p1[r]) + bl2[c];
            }
        }
    }
}

// ---------------- launch ----------------

extern "C" void kernel_launch(void* const* d_in, const int* in_sizes, int n_in,
                              void* d_out, int out_size, void* d_ws, size_t ws_size,
                              hipStream_t stream) {
    const float* x   = (const float*)d_in[0];
    const int* esrc  = (const int*)d_in[1];
    const int* edst  = (const int*)d_in[2];
    const float* ew1 = (const float*)d_in[3];
    const float* ew2 = (const float*)d_in[4];
    const float* W1  = (const float*)d_in[5];
    const float* b1  = (const float*)d_in[6];
    const float* W2  = (const float*)d_in[7];
    const float* b2  = (const float*)d_in[8];
    const float* Wl1 = (const float*)d_in[9];
    const float* bl1 = (const float*)d_in[10];
    const float* Wl2 = (const float*)d_in[11];
    const float* bl2 = (const float*)d_in[12];
    float* out = (float*)d_out;

    char* p = (char*)d_ws;
    ushort* Af      = (ushort*)p;          p += (size_t)N_NODES * D * 2;   // agg (fp16)
    ushort* h1f     = (ushort*)p;          p += (size_t)N_NODES * D * 2;   // h1 (fp16)
    ushort* xf      = (ushort*)p;          p += (size_t)N_NODES * D * 2;   // x (fp16)
    int* row_ptr    = (int*)p;             p += (size_t)(N_NODES + 16) * 4;
    int* blockhist  = (int*)p;             p += (size_t)SCAN_TOT * 4;      // 307 KB
    int* partials   = (int*)p;             p += 128 * 4;
    uint2* part     = (uint2*)p;           p += (size_t)N_EDGES * 8;       // 12.8 MB
    uint2* packed   = (uint2*)p;           p += (size_t)N_EDGES * 8;       // 12.8 MB
    ushort* W1t     = (ushort*)p;          p += 2 * D * D * 2;
    ushort* W2t     = (ushort*)p;          p += 2 * D * D * 2;
    ushort* Wl1t    = (ushort*)p;          p += D * D * 2;

    // CSR build: two-level partition, LDS atomics only, hierarchical scan
    p1_hist<<<NCHUNK, 256, 0, stream>>>(edst, blockhist);
    scan_a<<<SC_NB, 256, 0, stream>>>(blockhist, partials);
    scan_b<<<1, 128, 0, stream>>>(partials, row_ptr);
    scan_c<<<SC_NB, 256, 0, stream>>>(blockhist, partials);
    p1_scatter<<<NCHUNK, 256, 0, stream>>>(esrc, edst, ew1, ew2, blockhist, part);
    p2_kernel<<<NBIN, 256, 0, stream>>>(blockhist, part, row_ptr, packed);

    cvt_f16_kernel<<<(N_NODES * D) / (256 * 8), 256, 0, stream>>>(x, xf);
    wtile_kernel<<<(2 * D * D + 255) / 256, 256, 0, stream>>>(W1, W1t, 2 * D * D);
    wtile_kernel<<<(2 * D * D + 255) / 256, 256, 0, stream>>>(W2, W2t, 2 * D * D);
    wtile_kernel<<<(D * D + 255) / 256, 256, 0, stream>>>(Wl1, Wl1t, D * D);

    int ggrid = (N_NODES + 127) / 128;   // 782

    // layer 1
    spmm_kernel<<<N_NODES / 4, 256, 0, stream>>>(xf, packed, row_ptr, Af, 0);
    gemm_mfma_kernel<<<ggrid, 256, 0, stream>>>(xf, Af, W1t, b1, h1f);
    // layer 2 + classifier fused (h2 never touches global memory)
    spmm_kernel<<<N_NODES / 4, 256, 0, stream>>>(h1f, packed, row_ptr, Af, 1);
    gemm2_cls_kernel<<<ggrid, 256, 0, stream>>>(h1f, Af, W2t, b2, Wl1t, bl1, Wl2, bl2, out);
}

// Round 12
// 248.509 us; speedup vs baseline: 1.7799x; 1.1841x over previous
//
#include <hip/hip_runtime.h>
#include <hip/hip_fp16.h>

#define N_NODES 100000
#define N_EDGES 1600000
#define D 128

#define NBIN 196            // coarse bins: dst>>9, 512 nodes each
#define NCHUNK 391          // edge chunks of 4096
#define CHUNK_E 4096
#define SCAN_TOT (NBIN * NCHUNK)   // 76636
#define SC_NB ((SCAN_TOT + 1023) / 1024)   // 75

typedef __attribute__((ext_vector_type(8))) _Float16 f16x8;
typedef __attribute__((ext_vector_type(4))) float f32x4;
typedef __attribute__((ext_vector_type(8))) unsigned short u16x8;

__device__ __forceinline__ float h2f(ushort u) {
    __half_raw r; r.x = u;
    return __half2float(__half(r));
}
__device__ __forceinline__ ushort f2h(float f) {
    __half_raw r = __half_raw(__float2half(f));
    return r.x;
}

// ---------------- P1: coarse partition (LDS histograms, no global atomics) ---------

__global__ __launch_bounds__(256) void p1_hist(const int* __restrict__ dst,
                                               int* __restrict__ blockhist) {
    __shared__ int h[NBIN];
    int tid = threadIdx.x;
    for (int b = tid; b < NBIN; b += 256) h[b] = 0;
    __syncthreads();
    int base = blockIdx.x * CHUNK_E;
#pragma unroll
    for (int j = 0; j < 16; ++j) {
        int i = base + j * 256 + tid;
        if (i < N_EDGES) atomicAdd(&h[dst[i] >> 9], 1);
    }
    __syncthreads();
    for (int b = tid; b < NBIN; b += 256)
        blockhist[b * NCHUNK + blockIdx.x] = h[b];
}

// ---- hierarchical exclusive scan of blockhist[SCAN_TOT] (in place) ----

__global__ __launch_bounds__(256) void scan_a(const int* __restrict__ bh,
                                              int* __restrict__ partials) {
    __shared__ int sums[256];
    int tid = threadIdx.x;
    int base = blockIdx.x * 1024 + tid * 4;
    int s = 0;
#pragma unroll
    for (int i = 0; i < 4; ++i) {
        int idx = base + i;
        if (idx < SCAN_TOT) s += bh[idx];
    }
    sums[tid] = s;
    __syncthreads();
#pragma unroll
    for (int off = 128; off > 0; off >>= 1) {
        if (tid < off) sums[tid] += sums[tid + off];
        __syncthreads();
    }
    if (tid == 0) partials[blockIdx.x] = sums[0];
}

__global__ __launch_bounds__(128) void scan_b(int* __restrict__ partials,
                                              int* __restrict__ row_ptr) {
    __shared__ int s[128];
    int tid = threadIdx.x;
    int v = (tid < SC_NB) ? partials[tid] : 0;
    s[tid] = v;
    __syncthreads();
    for (int off = 1; off < 128; off <<= 1) {
        int t = (tid >= off) ? s[tid - off] : 0;
        __syncthreads();
        s[tid] += t;
        __syncthreads();
    }
    if (tid < SC_NB) partials[tid] = s[tid] - v;   // exclusive block offsets
    if (tid == 0) row_ptr[N_NODES] = N_EDGES;
}

__global__ __launch_bounds__(256) void scan_c(int* __restrict__ bh,
                                              const int* __restrict__ partials) {
    __shared__ int tsum[256];
    int tid = threadIdx.x;
    int base = blockIdx.x * 1024 + tid * 4;
    int d[4];
#pragma unroll
    for (int i = 0; i < 4; ++i)
        d[i] = (base + i < SCAN_TOT) ? bh[base + i] : 0;
    int s = d[0] + d[1] + d[2] + d[3];
    tsum[tid] = s;
    __syncthreads();
    for (int off = 1; off < 256; off <<= 1) {
        int t = (tid >= off) ? tsum[tid - off] : 0;
        __syncthreads();
        tsum[tid] += t;
        __syncthreads();
    }
    int run = partials[blockIdx.x] + tsum[tid] - s;   // exclusive start
#pragma unroll
    for (int i = 0; i < 4; ++i) {
        int idx = base + i;
        if (idx < SCAN_TOT) {
            bh[idx] = run;
            run += d[i];
        }
    }
}

// record: {src | dstLocal<<17, w1h | w2h<<16}
__global__ __launch_bounds__(256) void p1_scatter(const int* __restrict__ src,
                                                  const int* __restrict__ dst,
                                                  const float* __restrict__ w1,
                                                  const float* __restrict__ w2,
                                                  const int* __restrict__ bh,
                                                  uint2* __restrict__ part) {
    __shared__ int cur[NBIN];
    int tid = threadIdx.x;
    for (int b = tid; b < NBIN; b += 256) cur[b] = bh[b * NCHUNK + blockIdx.x];
    __syncthreads();
    int base = blockIdx.x * CHUNK_E;
#pragma unroll
    for (int j = 0; j < 16; ++j) {
        int i = base + j * 256 + tid;
        if (i < N_EDGES) {
            int d = dst[i];
            int pos = atomicAdd(&cur[d >> 9], 1);
            uint2 e;
            e.x = (unsigned)src[i] | ((unsigned)(d & 511) << 17);
            e.y = (unsigned)f2h(w1[i]) | ((unsigned)f2h(w2[i]) << 16);
            part[pos] = e;
        }
    }
}

// ---------------- P2: per-bin fine grouping -> exact CSR, deg_inv folded ----------

__global__ __launch_bounds__(256) void p2_kernel(const int* __restrict__ bh,
                                                 const uint2* __restrict__ part,
                                                 int* __restrict__ row_ptr,
                                                 uint2* __restrict__ packed) {
    __shared__ int deg2[512];
    __shared__ int cur[512];
    __shared__ int sb[256];
    int tid = threadIdx.x;
    int bin = blockIdx.x;
    int base = bh[bin * NCHUNK];
    int endv = (bin == NBIN - 1) ? N_EDGES : bh[(bin + 1) * NCHUNK];
    int cnt = endv - base;
    deg2[tid] = 0; deg2[tid + 256] = 0;
    __syncthreads();
    for (int k = tid; k < cnt; k += 256)
        atomicAdd(&deg2[part[base + k].x >> 17], 1);
    __syncthreads();
    int s0 = deg2[2 * tid], s1 = deg2[2 * tid + 1];
    int ts = s0 + s1;
    sb[tid] = ts;
    __syncthreads();
    for (int off = 1; off < 256; off <<= 1) {
        int v = (tid >= off) ? sb[tid - off] : 0;
        __syncthreads();
        sb[tid] += v;
        __syncthreads();
    }
    int ex = sb[tid] - ts;                     // exclusive within bin
    cur[2 * tid] = ex;
    cur[2 * tid + 1] = ex + s0;
    int node0 = bin * 512 + 2 * tid;
    if (node0 < N_NODES)     row_ptr[node0]     = base + ex;
    if (node0 + 1 < N_NODES) row_ptr[node0 + 1] = base + ex + s0;
    __syncthreads();
    for (int k = tid; k < cnt; k += 256) {
        uint2 r = part[base + k];
        int local = r.x >> 17;
        float di = 1.0f / (float)deg2[local];
        int pos = base + atomicAdd(&cur[local], 1);
        uint2 e;
        e.x = r.x & 0x1FFFFu;
        e.y = (unsigned)f2h(h2f((ushort)(r.y & 0xFFFFu)) * di)
            | ((unsigned)f2h(h2f((ushort)(r.y >> 16)) * di) << 16);
        packed[pos] = e;
    }
}

// ---------------- fp32 -> fp16 convert (8 elems/thread) ----------------

__global__ __launch_bounds__(256) void cvt_f16_kernel(const float* __restrict__ in,
                                                      ushort* __restrict__ out) {
    long i = ((long)blockIdx.x * 256 + threadIdx.x) * 8;
    const float4 a = *reinterpret_cast<const float4*>(&in[i]);
    const float4 b = *reinterpret_cast<const float4*>(&in[i + 4]);
    ushort4 u0, u1;
    u0.x = f2h(a.x); u0.y = f2h(a.y); u0.z = f2h(a.z); u0.w = f2h(a.w);
    u1.x = f2h(b.x); u1.y = f2h(b.y); u1.z = f2h(b.z); u1.w = f2h(b.w);
    *reinterpret_cast<ushort4*>(&out[i]) = u0;
    *reinterpret_cast<ushort4*>(&out[i + 4]) = u1;
}

// ---------------- W tiling: fragment-ordered fp16 (all 3 tables, one launch) ------
// addr(k,n) = ((k>>3)*128 + n)*8 + (k&7)

__global__ __launch_bounds__(256) void wtile_all_kernel(const float* __restrict__ W1,
                                                        const float* __restrict__ W2,
                                                        const float* __restrict__ Wl1,
                                                        ushort* __restrict__ W1t,
                                                        ushort* __restrict__ W2t,
                                                        ushort* __restrict__ Wl1t) {
    int i = blockIdx.x * 256 + threadIdx.x;
    const int DD2 = 2 * D * D;
    const float* src; ushort* dstp; int j;
    if (i < DD2)               { src = W1;  dstp = W1t;  j = i; }
    else if (i < 2 * DD2)      { src = W2;  dstp = W2t;  j = i - DD2; }
    else if (i < 2 * DD2 + D * D) { src = Wl1; dstp = Wl1t; j = i - 2 * DD2; }
    else return;
    int k = j >> 7, n = j & 127;
    int addr = (((k >> 3) << 7) + n) * 8 + (k & 7);
    dstp[addr] = f2h(src[j]);
}

// ---------------- SpMM: CSR gather of fp16 rows + leaky-relu ----------------
// wave-per-node; 16 lanes cover a row (ushort8/lane); lane>>4 = edge parity (4-way).

__global__ __launch_bounds__(256) void spmm_kernel(const ushort* __restrict__ xin,
                                                   const uint2* __restrict__ edges,
                                                   const int* __restrict__ row_ptr,
                                                   ushort* __restrict__ out,
                                                   int widx) {
    int wid = threadIdx.x >> 6;
    int lane = threadIdx.x & 63;
    int par = lane >> 4;                   // edge parity 0..3
    int dl = lane & 15;                    // dim group: dims 8*dl..8*dl+7
    int n = blockIdx.x * 4 + wid;
    int beg = row_ptr[n], end = row_ptr[n + 1];
    float a[8] = {0.f, 0.f, 0.f, 0.f, 0.f, 0.f, 0.f, 0.f};

    int i = beg;
    for (; i + 15 < end; i += 16) {
        const uint2 e0 = edges[i + par];
        const uint2 e1 = edges[i + 4 + par];
        const uint2 e2 = edges[i + 8 + par];
        const uint2 e3 = edges[i + 12 + par];
        float w0 = h2f((ushort)(widx ? (e0.y >> 16) : (e0.y & 0xFFFFu)));
        float w1 = h2f((ushort)(widx ? (e1.y >> 16) : (e1.y & 0xFFFFu)));
        float w2 = h2f((ushort)(widx ? (e2.y >> 16) : (e2.y & 0xFFFFu)));
        float w3 = h2f((ushort)(widx ? (e3.y >> 16) : (e3.y & 0xFFFFu)));
        const u16x8 u0 = *reinterpret_cast<const u16x8*>(&xin[(long)e0.x * D + dl * 8]);
        const u16x8 u1 = *reinterpret_cast<const u16x8*>(&xin[(long)e1.x * D + dl * 8]);
        const u16x8 u2 = *reinterpret_cast<const u16x8*>(&xin[(long)e2.x * D + dl * 8]);
        const u16x8 u3 = *reinterpret_cast<const u16x8*>(&xin[(long)e3.x * D + dl * 8]);
#pragma unroll
        for (int j = 0; j < 8; ++j)
            a[j] += w0 * h2f(u0[j]) + w1 * h2f(u1[j]) + w2 * h2f(u2[j]) + w3 * h2f(u3[j]);
    }
    for (; i + 7 < end; i += 8) {
        const uint2 e0 = edges[i + par];
        const uint2 e1 = edges[i + 4 + par];
        float w0 = h2f((ushort)(widx ? (e0.y >> 16) : (e0.y & 0xFFFFu)));
        float w1 = h2f((ushort)(widx ? (e1.y >> 16) : (e1.y & 0xFFFFu)));
        const u16x8 u0 = *reinterpret_cast<const u16x8*>(&xin[(long)e0.x * D + dl * 8]);
        const u16x8 u1 = *reinterpret_cast<const u16x8*>(&xin[(long)e1.x * D + dl * 8]);
#pragma unroll
        for (int j = 0; j < 8; ++j)
            a[j] += w0 * h2f(u0[j]) + w1 * h2f(u1[j]);
    }
    for (; i < end; i += 4) {
        int idx = i + par;
        bool act = idx < end;
        const uint2 e0 = edges[act ? idx : end - 1];
        float w0 = act ? h2f((ushort)(widx ? (e0.y >> 16) : (e0.y & 0xFFFFu))) : 0.f;
        const u16x8 u0 = *reinterpret_cast<const u16x8*>(&xin[(long)e0.x * D + dl * 8]);
#pragma unroll
        for (int j = 0; j < 8; ++j)
            a[j] += w0 * h2f(u0[j]);
    }

#pragma unroll
    for (int j = 0; j < 8; ++j) {
        a[j] += __shfl_xor(a[j], 16, 64);
        a[j] += __shfl_xor(a[j], 32, 64);
    }

    if (par == 0) {
        ushort4 r0, r1;
        float v;
        v = a[0]; v = v > 0.f ? v : 0.01f * v; r0.x = f2h(v);
        v = a[1]; v = v > 0.f ? v : 0.01f * v; r0.y = f2h(v);
        v = a[2]; v = v > 0.f ? v : 0.01f * v; r0.z = f2h(v);
        v = a[3]; v = v > 0.f ? v : 0.01f * v; r0.w = f2h(v);
        v = a[4]; v = v > 0.f ? v : 0.01f * v; r1.x = f2h(v);
        v = a[5]; v = v > 0.f ? v : 0.01f * v; r1.y = f2h(v);
        v = a[6]; v = v > 0.f ? v : 0.01f * v; r1.z = f2h(v);
        v = a[7]; v = v > 0.f ? v : 0.01f * v; r1.w = f2h(v);
        *reinterpret_cast<ushort4*>(&out[(long)n * D + dl * 8]) = r0;
        *reinterpret_cast<ushort4*>(&out[(long)n * D + dl * 8 + 4]) = r1;
    }
}

// ---------------- MFMA fp16 GEMM: 16 rows per wave (occupancy-oriented) ----------
// out = relu([in1|in2] @ W + b) as fp16. Grid: ceil(N/64) blocks x 4 waves.

__global__ __launch_bounds__(256) void gemm_mfma_kernel(
        const ushort* __restrict__ in1,
        const ushort* __restrict__ in2,
        const ushort* __restrict__ Wt,
        const float* __restrict__ bias,
        ushort* __restrict__ outp) {
    int tid = threadIdx.x;
    int w = tid >> 6, l = tid & 63;
    int c = l & 15, kg = l >> 4;
    int base_m = blockIdx.x * 64 + w * 16;
    int r0 = base_m + c;  if (r0 >= N_NODES) r0 = N_NODES - 1;

    f32x4 acc[8];
#pragma unroll
    for (int ni = 0; ni < 8; ++ni) acc[ni] = (f32x4)0.f;

    for (int ks = 0; ks < 8; ++ks) {
        int kb = (ks & 3) * 32 + kg * 8;
        const ushort* src = (ks < 4) ? in1 : in2;
        f16x8 a0 = *reinterpret_cast<const f16x8*>(&src[(long)r0 * D + kb]);
        const ushort* wb = &Wt[(size_t)((ks * 4 + kg) * 128) * 8];
#pragma unroll
        for (int ni = 0; ni < 8; ++ni) {
            const f16x8 b = *reinterpret_cast<const f16x8*>(&wb[(ni * 16 + c) * 8]);
            acc[ni] = __builtin_amdgcn_mfma_f32_16x16x32_f16(a0, b, acc[ni], 0, 0, 0);
        }
    }

    float bv[8];
#pragma unroll
    for (int ni = 0; ni < 8; ++ni) bv[ni] = bias[ni * 16 + c];
    int rowb = base_m + kg * 4;
#pragma unroll
    for (int r = 0; r < 4; ++r) {
        int row = rowb + r;
        if (row < N_NODES) {
#pragma unroll
            for (int ni = 0; ni < 8; ++ni) {
                float v = acc[ni][r] + bv[ni];
                v = v > 0.f ? v : 0.f;
                outp[(long)row * D + ni * 16 + c] = f2h(v);
            }
        }
    }
}

// ---------------- Fused layer-2 GEMM + classifier (16 rows per wave) ----------
// Phase A: h2 = relu([h1|A] @ W2 + b2) -> per-wave LDS tile (never to global)
// Phase B: out = relu(h2 @ Wl1 + bl1) @ Wl2 + bl2

#define LSTR 136   // LDS row stride in shorts

__global__ __launch_bounds__(256) void gemm2_cls_kernel(
        const ushort* __restrict__ in1,
        const ushort* __restrict__ in2,
        const ushort* __restrict__ W2t,
        const float* __restrict__ b2,
        const ushort* __restrict__ Wl1t,
        const float* __restrict__ bl1,
        const float* __restrict__ Wl2,
        const float* __restrict__ bl2,
        float* __restrict__ out) {
    __shared__ __align__(16) ushort lds_h2[4][16][LSTR];
    int tid = threadIdx.x;
    int w = tid >> 6, l = tid & 63;
    int c = l & 15, kg = l >> 4;
    int base_m = blockIdx.x * 64 + w * 16;
    int r0 = base_m + c;  if (r0 >= N_NODES) r0 = N_NODES - 1;

    // ---- phase A: h2 fragments ----
    f32x4 acc[8];
#pragma unroll
    for (int ni = 0; ni < 8; ++ni) acc[ni] = (f32x4)0.f;

    for (int ks = 0; ks < 8; ++ks) {
        int kb = (ks & 3) * 32 + kg * 8;
        const ushort* src = (ks < 4) ? in1 : in2;
        f16x8 a0 = *reinterpret_cast<const f16x8*>(&src[(long)r0 * D + kb]);
        const ushort* wb = &W2t[(size_t)((ks * 4 + kg) * 128) * 8];
#pragma unroll
        for (int ni = 0; ni < 8; ++ni) {
            const f16x8 b = *reinterpret_cast<const f16x8*>(&wb[(ni * 16 + c) * 8]);
            acc[ni] = __builtin_amdgcn_mfma_f32_16x16x32_f16(a0, b, acc[ni], 0, 0, 0);
        }
    }

    float bv[8];
#pragma unroll
    for (int ni = 0; ni < 8; ++ni) bv[ni] = b2[ni * 16 + c];
#pragma unroll
    for (int r = 0; r < 4; ++r) {
        int lrow = kg * 4 + r;
#pragma unroll
        for (int ni = 0; ni < 8; ++ni) {
            float v = acc[ni][r] + bv[ni];
            v = v > 0.f ? v : 0.f;
            lds_h2[w][lrow][ni * 16 + c] = f2h(v);
        }
    }
    __syncthreads();

    // ---- phase B: classifier on the wave's 16 h2 rows ----
    f32x4 bcc[8];
#pragma unroll
    for (int ni = 0; ni < 8; ++ni) bcc[ni] = (f32x4)0.f;

    for (int ks = 0; ks < 4; ++ks) {
        int kb = ks * 32 + kg * 8;
        f16x8 a0 = *reinterpret_cast<const f16x8*>(&lds_h2[w][c][kb]);
        const ushort* wb = &Wl1t[(size_t)((ks * 4 + kg) * 128) * 8];
#pragma unroll
        for (int ni = 0; ni < 8; ++ni) {
            const f16x8 b = *reinterpret_cast<const f16x8*>(&wb[(ni * 16 + c) * 8]);
            bcc[ni] = __builtin_amdgcn_mfma_f32_16x16x32_f16(a0, b, bcc[ni], 0, 0, 0);
        }
    }

    float b1v[8]; float2 w2v[8];
#pragma unroll
    for (int ni = 0; ni < 8; ++ni) {
        b1v[ni] = bl1[ni * 16 + c];
        w2v[ni] = *reinterpret_cast<const float2*>(&Wl2[(ni * 16 + c) * 2]);
    }
    float p0[4] = {0.f, 0.f, 0.f, 0.f};
    float p1[4] = {0.f, 0.f, 0.f, 0.f};
#pragma unroll
    for (int ni = 0; ni < 8; ++ni) {
#pragma unroll
        for (int r = 0; r < 4; ++r) {
            float t = bcc[ni][r] + b1v[ni];
            t = t > 0.f ? t : 0.f;
            p0[r] += t * w2v[ni].x;
            p1[r] += t * w2v[ni].y;
        }
    }
#pragma unroll
    for (int r = 0; r < 4; ++r) {
#pragma unroll
        for (int m = 1; m < 16; m <<= 1) {
            p0[r] += __shfl_xor(p0[r], m, 64);
            p1[r] += __shfl_xor(p1[r], m, 64);
        }
    }
    if (c < 2) {
        int rowb = base_m + kg * 4;
#pragma unroll
        for (int r = 0; r < 4; ++r) {
            int row = rowb + r;
            if (row < N_NODES)
                out[(long)row * 2 + c] = (c == 0 ? p0[r] : p1[r]) + bl2[c];
        }
    }
}

// ---------------- launch ----------------

extern "C" void kernel_launch(void* const* d_in, const int* in_sizes, int n_in,
                              void* d_out, int out_size, void* d_ws, size_t ws_size,
                              hipStream_t stream) {
    const float* x   = (const float*)d_in[0];
    const int* esrc  = (const int*)d_in[1];
    const int* edst  = (const int*)d_in[2];
    const float* ew1 = (const float*)d_in[3];
    const float* ew2 = (const float*)d_in[4];
    const float* W1  = (const float*)d_in[5];
    const float* b1  = (const float*)d_in[6];
    const float* W2  = (const float*)d_in[7];
    const float* b2  = (const float*)d_in[8];
    const float* Wl1 = (const float*)d_in[9];
    const float* bl1 = (const float*)d_in[10];
    const float* Wl2 = (const float*)d_in[11];
    const float* bl2 = (const float*)d_in[12];
    float* out = (float*)d_out;

    char* p = (char*)d_ws;
    ushort* Af      = (ushort*)p;          p += (size_t)N_NODES * D * 2;   // agg (fp16)
    ushort* h1f     = (ushort*)p;          p += (size_t)N_NODES * D * 2;   // h1 (fp16)
    ushort* xf      = (ushort*)p;          p += (size_t)N_NODES * D * 2;   // x (fp16)
    int* row_ptr    = (int*)p;             p += (size_t)(N_NODES + 16) * 4;
    int* blockhist  = (int*)p;             p += (size_t)SCAN_TOT * 4;      // 307 KB
    int* partials   = (int*)p;             p += 128 * 4;
    uint2* part     = (uint2*)p;           p += (size_t)N_EDGES * 8;       // 12.8 MB
    uint2* packed   = (uint2*)p;           p += (size_t)N_EDGES * 8;       // 12.8 MB
    ushort* W1t     = (ushort*)p;          p += 2 * D * D * 2;
    ushort* W2t     = (ushort*)p;          p += 2 * D * D * 2;
    ushort* Wl1t    = (ushort*)p;          p += D * D * 2;

    // CSR build: two-level partition, LDS atomics only, hierarchical scan
    p1_hist<<<NCHUNK, 256, 0, stream>>>(edst, blockhist);
    scan_a<<<SC_NB, 256, 0, stream>>>(blockhist, partials);
    scan_b<<<1, 128, 0, stream>>>(partials, row_ptr);
    scan_c<<<SC_NB, 256, 0, stream>>>(blockhist, partials);
    p1_scatter<<<NCHUNK, 256, 0, stream>>>(esrc, edst, ew1, ew2, blockhist, part);
    p2_kernel<<<NBIN, 256, 0, stream>>>(blockhist, part, row_ptr, packed);

    cvt_f16_kernel<<<(N_NODES * D) / (256 * 8), 256, 0, stream>>>(x, xf);
    wtile_all_kernel<<<(5 * D * D + 255) / 256, 256, 0, stream>>>(W1, W2, Wl1,
                                                                  W1t, W2t, Wl1t);

    int ggrid = (N_NODES + 63) / 64;   // 1563

    // layer 1
    spmm_kernel<<<N_NODES / 4, 256, 0, stream>>>(xf, packed, row_ptr, Af, 0);
    gemm_mfma_kernel<<<ggrid, 256, 0, stream>>>(xf, Af, W1t, b1, h1f);
    // layer 2 + classifier fused (h2 never touches global memory)
    spmm_kernel<<<N_NODES / 4, 256, 0, stream>>>(h1f, packed, row_ptr, Af, 1);
    gemm2_cls_kernel<<<ggrid, 256, 0, stream>>>(h1f, Af, W2t, b2, Wl1t, bl1, Wl2, bl2, out);
}